// Round 6
// baseline (13408.595 us; speedup 1.0000x reference)
//
#include <hip/hip_runtime.h>
#include <stdint.h>

// DeepAR decoder: L=3, B=512, H=1024, TAU=96, T=8, BETA=2
// ws layout (bytes):
//   Wih_b  bf16 [3][4096][1024]   @ 0          (25165824)
//   Whh_b  bf16 [3][4096][1024]   @ 25165824   (25165824)
//   h_b    bf16 [3][512][1024]    @ 50331648   (3145728)
//   c_s    f32  [3][512][1024]    @ 53477376   (6291456)
//   gbuf   f32  [3][8M]           @ 59768832   (25165824)  (MFMA C-layout tiles)
//   bias   f32  [3][4096]         @ 84934656   (49152)
//   macc   f32  [512][96][16]     @ 84983808   (3145728)
//   bar    u32[8] stride 32       @ 88129536   (1024)      per-XCD phase counters
//   tick   u32[8] stride 32       @ 88130560   (1024)      per-XCD ticket counters

typedef __attribute__((ext_vector_type(8))) short short8;
typedef __attribute__((ext_vector_type(8))) __bf16 bf16x8_t;
typedef __attribute__((ext_vector_type(4))) float f32x4;
typedef __attribute__((ext_vector_type(4))) unsigned short u16x4;

static __device__ __forceinline__ unsigned short f2bf(float f) {
  unsigned int u = __float_as_uint(f);
  u += 0x7FFFu + ((u >> 16) & 1u);  // RNE
  return (unsigned short)(u >> 16);
}

static __device__ __forceinline__ float sigm(float x) {
  return 1.0f / (1.0f + __expf(-x));
}
static __device__ __forceinline__ float tanh_f(float x) {
  float xc = fminf(fmaxf(x, -15.f), 15.f);
  float e = __expf(2.0f * xc);
  return 1.0f - 2.0f / (e + 1.0f);
}

// aux=1 (sc0/GLC): bypass L1, read the XCD's L2 directly. All cross-BLOCK
// data in this design is same-XCD, so L2 is the coherence point.
static __device__ __forceinline__ void gload_lds16_sc0(const void* g, void* l) {
  __builtin_amdgcn_global_load_lds(
      (const __attribute__((address_space(1))) unsigned int*)g,
      (__attribute__((address_space(3))) unsigned int*)l, 16, 0, 1);
}

static __device__ __forceinline__ f32x4 ld4_sc0(const float* p) {
  f32x4 r;
  asm volatile("global_load_dwordx4 %0, %1, off sc0"
               : "=v"(r) : "v"(p) : "memory");
  return r;
}
#define VMCNT0 asm volatile("s_waitcnt vmcnt(0)" ::: "memory")

static __device__ __forceinline__ f32x4 mfma16(short8 a, short8 b, f32x4 c) {
  return __builtin_amdgcn_mfma_f32_16x16x32_bf16((bf16x8_t)a, (bf16x8_t)b, c, 0, 0, 0);
}

// ---------------------------------------------------------------------------
// PERSISTENT kernel, XCD-LOCAL dataflow, 2 blocks/CU (round-5 counters:
// Occupancy 11.9%, MfmaUtil 10.7%, all pipes idle -> latency-bound; this
// N-splits the round-5 tile 64x64 -> 64x32 cols so two blocks co-reside).
//
// grid 512, 256 thr, ~64 KB LDS/block -> pigeonhole forces exactly 2
// blocks/CU (3x64KB > 160KB), so each XCD hosts exactly 64 blocks.
// Work decode: mt = XCC_ID (HW-truthful), ticket 0..63 per XCD:
//   role = ticket&1 (0 = x-GEMM+epilogue, 1 = h-partial)
//   hcg5 = ticket>>1 (0..31), hc0 = hcg5*32  (32 h-cols per block)
// Block tile: 64 batch rows x (4 gates x 32 h-cols). Waves: cg=w&1 col-half
// (16 cols), rh=w>>1 row-half (32 rows); acc[2][4]. B strip per wave is the
// same 16-col load pattern as round 5 (bfr[4][4], depth-4) — only the column
// base changes. STAGE/A-LDS swizzle path byte-identical to round 5.
//
// XCD-locality (verified in round 5): all touchers of h_b rows [64*mt,+64),
// c_s rows, gbuf tiles (hcg5,mt) are on ONE XCD => sc0 loads vs L2 suffice;
// per-XCD 64-way monotonic barrier, no fences.
// ---------------------------------------------------------------------------
__global__ __launch_bounds__(256, 2) void persist_kernel(
    const unsigned short* __restrict__ WihA,  // [3][4096][1024] bf16
    const unsigned short* __restrict__ WhhA,  // [3][4096][1024] bf16
    unsigned short* __restrict__ hB,          // [3][512][1024] bf16
    float* __restrict__ cS,                   // [3][512][1024]
    float* __restrict__ gB,                   // [3][2097152]
    const float* __restrict__ biasA,          // [3][4096]
    float* __restrict__ macc,                 // [512][96][16]
    const float* __restrict__ W1, const float* __restrict__ W2,
    unsigned* __restrict__ bar) {             // [8*32] bar | [8*32] tick
  __shared__ __align__(16) char ldsA[2][32768];  // A chunk 64x256 bf16, dbuf
  __shared__ int shmeta[4];

  unsigned xcc;
  asm volatile("s_getreg_b32 %0, hwreg(HW_REG_XCC_ID)" : "=s"(xcc));
  xcc &= 7u;

  if (threadIdx.x == 0) {
    unsigned t = __hip_atomic_fetch_add(bar + 256 + xcc * 32, 1u,
                                        __ATOMIC_RELAXED,
                                        __HIP_MEMORY_SCOPE_AGENT);
    shmeta[0] = (int)t;
  }
  __syncthreads();
  const int ticket = shmeta[0];      // 0..63 within this XCD
  const int mt = (int)xcc;           // m-tile 0..7 (64 batch rows)
  const int role = ticket & 1;       // 0 = x-GEMM+epilogue, 1 = h-partial
  const int hcg5 = ticket >> 1;      // 0..31 (32 h-cols)
  const int tile = hcg5 * 8 + mt;    // gbuf tile id (32-col tiles), 0..255
  const int m0 = mt * 64;
  const int hc0 = hcg5 * 32;
  unsigned* mybar = bar + xcc * 32;

  const int tid = threadIdx.x;
  const int w = tid >> 6;   // wave id
  const int cg = w & 1;     // col-half (16 cols)
  const int rh = w >> 1;    // row-half (32 rows)
  const int lane = tid & 63;
  const int quad = lane >> 4;
  const int l16 = lane & 15;
  const int rbase = tid >> 5;  // 0..7
  const int spos = tid & 31;
  const int wvbase = w * 1024;  // wave-uniform LDS offset within issue
  const int rx0 = l16, rx1 = 16 + l16;

// STAGE: byte-identical to round 5 (64 rows x 256 k bf16 = 32 KB chunk)
#define STAGE(kc_, buf_)                                                      \
  {                                                                           \
    _Pragma("unroll") for (int j = 0; j < 8; ++j) {                           \
      int r_ = j * 8 + rbase;                                                 \
      int c_ = spos ^ (r_ & 31);                                              \
      gload_lds16_sc0(Ap + (size_t)(m0 + r_) * 1024 + (kc_)*256 + c_ * 8,     \
                      &ldsA[buf_][j * 4096 + wvbase]);                        \
    }                                                                         \
  }

#pragma unroll 1
  for (int p = 0; p < 289; ++p) {
    // p=0: bootstrap (h-partial only, l=2 semantics); p>=1: st=(p-1)/3, l=(p-1)%3
    const int l = (p == 0) ? 2 : (p - 1) % 3;
    const int st = (p == 0) ? 0 : (p - 1) / 3;
    const int lh = (l + 1) % 3;
    const int do_x = (p != 0);
    const int do_h = (p != 288);
    const int do_proj = (p != 0) && (l == 2);
    const int active = role ? do_h : do_x;

    if (active) {
      const unsigned short* Wp;
      const unsigned short* Ap;
      if (role) {
        Wp = WhhA + (size_t)lh * 4194304;
        Ap = hB + (size_t)lh * 524288;
      } else {
        Wp = WihA + (size_t)l * 4194304;
        Ap = hB + (size_t)((l == 0) ? 2 : (l - 1)) * 524288;
      }

      // B rows (weights, direct-to-register): gate g, col hc0 + cg*16 + l16
      const unsigned short* brow[4];
#pragma unroll
      for (int g = 0; g < 4; ++g)
        brow[g] =
            Wp + (size_t)(g * 1024 + hc0 + cg * 16 + l16) * 1024 + quad * 8;

      // prologue: stage chunk 0, B prefetch depth 4, acc init
      STAGE(0, 0);
      short8 bfr[4][4];
#pragma unroll
      for (int d = 0; d < 4; ++d)
#pragma unroll
        for (int g = 0; g < 4; ++g) bfr[d][g] = *(const short8*)(brow[g] + d * 32);

      f32x4 acc[2][4];
      if (role == 0) {
        const float* gb_rd = gB + (size_t)l * 2097152;
#pragma unroll
        for (int mb = 0; mb < 2; ++mb)
#pragma unroll
          for (int g = 0; g < 4; ++g)
            acc[mb][g] = ld4_sc0(
                gb_rd +
                ((size_t)((tile * 2 + cg) * 16) + g * 4 + rh * 2 + mb) * 256 +
                lane * 4);
        VMCNT0;                              // asm loads valid before use
        __builtin_amdgcn_sched_barrier(0);   // rule #18: pin use after wait
      } else {
        f32x4 z4 = {0.f, 0.f, 0.f, 0.f};
#pragma unroll
        for (int mb = 0; mb < 2; ++mb)
#pragma unroll
          for (int g = 0; g < 4; ++g) acc[mb][g] = z4;
      }
      __syncthreads();  // chunk 0 staged

#pragma unroll
      for (int kc = 0; kc < 4; ++kc) {
        if (kc < 3) STAGE(kc + 1, (kc + 1) & 1);
        const char* base = ldsA[kc & 1];
        short8 afr[2][2];
#pragma unroll
        for (int mb = 0; mb < 2; ++mb) {
          int rxm = (mb & 1) ? rx1 : rx0;
          afr[0][mb] = *(const short8*)(base + (rh * 32 + mb * 16 + l16) * 512 +
                                        ((quad ^ rxm) << 4));
        }
#pragma unroll
        for (int ks = 0; ks < 8; ++ks) {
          const int kg = kc * 8 + ks;
          short8 a0 = afr[ks & 1][0], a1 = afr[ks & 1][1];
          short8 b0 = bfr[kg & 3][0], b1 = bfr[kg & 3][1];
          short8 b2 = bfr[kg & 3][2], b3 = bfr[kg & 3][3];
          if (ks < 7) {
#pragma unroll
            for (int mb = 0; mb < 2; ++mb) {
              int rxm = (mb & 1) ? rx1 : rx0;
              afr[(ks + 1) & 1][mb] =
                  *(const short8*)(base + (rh * 32 + mb * 16 + l16) * 512 +
                                   ((((ks + 1) * 4 + quad) ^ rxm) << 4));
            }
          }
          if (kg + 4 < 32) {  // depth-4 B prefetch
#pragma unroll
            for (int g = 0; g < 4; ++g)
              bfr[kg & 3][g] = *(const short8*)(brow[g] + (kg + 4) * 32);
          }
          acc[0][0] = mfma16(a0, b0, acc[0][0]);
          acc[1][0] = mfma16(a1, b0, acc[1][0]);
          acc[0][1] = mfma16(a0, b1, acc[0][1]);
          acc[1][1] = mfma16(a1, b1, acc[1][1]);
          acc[0][2] = mfma16(a0, b2, acc[0][2]);
          acc[1][2] = mfma16(a1, b2, acc[1][2]);
          acc[0][3] = mfma16(a0, b3, acc[0][3]);
          acc[1][3] = mfma16(a1, b3, acc[1][3]);
        }
        if (kc < 3) __syncthreads();
      }

      if (role == 1) {
        // recurrent partial -> gbuf (plain stores land in this XCD's L2;
        // consumer x-role is same-XCD and reads with sc0)
        float* gb_wr = gB + (size_t)lh * 2097152;
#pragma unroll
        for (int mb = 0; mb < 2; ++mb)
#pragma unroll
          for (int g = 0; g < 4; ++g)
            *(f32x4*)(gb_wr +
                      ((size_t)((tile * 2 + cg) * 16) + g * 4 + rh * 2 + mb) *
                          256 +
                      lane * 4) = acc[mb][g];
      } else {
        // ---- x-role epilogue: all 4 gates in-lane -> c,h (register only) ----
        float* c_l = cS + (size_t)l * 524288;
        unsigned short* h_out = hB + (size_t)l * 524288;
        const float* bias_l = biasA + l * 4096;
        const int colh = hc0 + cg * 16 + l16;
        float bs0 = bias_l[colh];
        float bs1 = bias_l[1024 + colh];
        float bs2 = bias_l[2048 + colh];
        float bs3 = bias_l[3072 + colh];
        float hv[8];
#pragma unroll
        for (int mb = 0; mb < 2; ++mb) {
#pragma unroll
          for (int rr = 0; rr < 4; ++rr) {
            int row = m0 + rh * 32 + mb * 16 + quad * 4 + rr;
            float gi = acc[mb][0][rr] + bs0;
            float gf = acc[mb][1][rr] + bs1;
            float gg = acc[mb][2][rr] + bs2;
            float go = acc[mb][3][rr] + bs3;
            float* cp = c_l + (size_t)row * 1024 + colh;
            float cn = sigm(gf) * (*cp) + sigm(gi) * tanh_f(gg);
            *cp = cn;
            float h = sigm(go) * tanh_f(cn);
            hv[mb * 4 + rr] = h;
            h_out[(size_t)row * 1024 + colh] = f2bf(h);
          }
        }

        if (do_proj) {
          // fused projection over this WG's 64 rows x 32 h-cols.
          float* hbuf = (float*)ldsA[0];     // 64*33*4 = 8448 B
          float* projred = (float*)ldsA[1];  // 4*64*17*4 = 17408 B
#pragma unroll
          for (int mb = 0; mb < 2; ++mb)
#pragma unroll
            for (int rr = 0; rr < 4; ++rr)
              hbuf[(rh * 32 + mb * 16 + quad * 4 + rr) * 33 + cg * 16 + l16] =
                  hv[mb * 4 + rr];
          __syncthreads();

          const int m = tid & 63;    // row within tile
          const int grp = tid >> 6;  // 4 groups of 8 h-cols
          float pm[8], ps[8];
          float hj[8];
#pragma unroll
          for (int j = 0; j < 8; ++j) hj[j] = hbuf[m * 33 + grp * 8 + j];
#pragma unroll
          for (int tt = 0; tt < 8; ++tt) {
            const f32x4* w1p = (const f32x4*)(W1 + tt * 1024 + hc0 + grp * 8);
            const f32x4* w2p = (const f32x4*)(W2 + tt * 1024 + hc0 + grp * 8);
            float s1 = 0.f, s2 = 0.f;
#pragma unroll
            for (int v = 0; v < 2; ++v) {
              f32x4 wa = w1p[v], wb = w2p[v];
#pragma unroll
              for (int j = 0; j < 4; ++j) {
                s1 += hj[v * 4 + j] * wa[j];
                s2 += hj[v * 4 + j] * wb[j];
              }
            }
            pm[tt] = s1;
            ps[tt] = s2;
          }
#pragma unroll
          for (int tt = 0; tt < 8; ++tt) {
            projred[(grp * 64 + m) * 17 + tt] = pm[tt];
            projred[(grp * 64 + m) * 17 + 8 + tt] = ps[tt];
          }
          __syncthreads();
#pragma unroll
          for (int q = 0; q < 4; ++q) {
            int s = grp * 4 + q;
            float v = projred[m * 17 + s] + projred[(64 + m) * 17 + s] +
                      projred[(128 + m) * 17 + s] + projred[(192 + m) * 17 + s];
            atomicAdd(&macc[((size_t)(m0 + m) * 96 + st) * 16 + s], v);
          }
        }
      }
    }

    // ---- per-XCD barrier (64 blocks), fence-free ----
    if (p < 288) {
      VMCNT0;           // this wave's stores drained to L2
      __syncthreads();  // all waves' stores drained before arrival
      if (tid == 0) {
        __hip_atomic_fetch_add(mybar, 1u, __ATOMIC_RELAXED,
                               __HIP_MEMORY_SCOPE_AGENT);
        const unsigned tgt = 64u * (unsigned)(p + 1);  // monotonic counter
        while (__hip_atomic_load(mybar, __ATOMIC_RELAXED,
                                 __HIP_MEMORY_SCOPE_AGENT) < tgt)
          __builtin_amdgcn_s_sleep(2);
      }
      asm volatile("" ::: "memory");  // no load hoisting above the spin
      __syncthreads();
    }
  }
#undef STAGE
}

// ---------------------------------------------------------------------------
__global__ void conv_w(const f32x4* __restrict__ wi, const f32x4* __restrict__ wh,
                       u16x4* __restrict__ wib, u16x4* __restrict__ whb) {
  int i = blockIdx.x * 256 + threadIdx.x;  // 3145728 vec4
  f32x4 a = wi[i], b = wh[i];
  u16x4 pa, pb;
#pragma unroll
  for (int j = 0; j < 4; ++j) {
    pa[j] = f2bf(a[j]);
    pb[j] = f2bf(b[j]);
  }
  wib[i] = pa;
  whb[i] = pb;
}

__global__ void init_state(const f32x4* __restrict__ hid, const f32x4* __restrict__ cel,
                           const f32x4* __restrict__ bih, const f32x4* __restrict__ bhh,
                           u16x4* __restrict__ hb, f32x4* __restrict__ cs,
                           f32x4* __restrict__ bias) {
  int i = blockIdx.x * 256 + threadIdx.x;  // 393216 vec4
  f32x4 h = hid[i];
  u16x4 p;
#pragma unroll
  for (int j = 0; j < 4; ++j) p[j] = f2bf(h[j]);
  hb[i] = p;
  cs[i] = cel[i];
  if (i < 3072) bias[i] = bih[i] + bhh[i];
}

__global__ void finalize_k(const float* __restrict__ macc, const float* __restrict__ b1,
                           const float* __restrict__ b2, float* __restrict__ out) {
  int idx = blockIdx.x * 256 + threadIdx.x;  // 393216 = 512*96*8
  int t = idx & 7;
  int bt = idx >> 3;  // b*96+tau
  float mu = macc[bt * 16 + t] + b1[t];
  float z2 = 2.0f * (macc[bt * 16 + 8 + t] + b2[t]);
  float sp = fmaxf(z2, 0.f) + log1pf(__expf(-fabsf(z2)));
  out[idx] = mu;
  out[393216 + idx] = 0.5f * sp;
}

// ---------------------------------------------------------------------------
extern "C" void kernel_launch(void* const* d_in, const int* in_sizes, int n_in,
                              void* d_out, int out_size, void* d_ws, size_t ws_size,
                              hipStream_t stream) {
  (void)in_sizes; (void)n_in; (void)out_size; (void)ws_size;
  const float* hidden = (const float*)d_in[0];
  const float* cell = (const float*)d_in[1];
  const float* Wih = (const float*)d_in[2];
  const float* Whh = (const float*)d_in[3];
  const float* bih = (const float*)d_in[4];
  const float* bhh = (const float*)d_in[5];
  const float* W1 = (const float*)d_in[6];
  const float* b1 = (const float*)d_in[7];
  const float* W2 = (const float*)d_in[8];
  const float* b2 = (const float*)d_in[9];
  float* out = (float*)d_out;

  char* ws = (char*)d_ws;
  unsigned short* Wih_b = (unsigned short*)(ws);
  unsigned short* Whh_b = (unsigned short*)(ws + 25165824);
  unsigned short* h_b = (unsigned short*)(ws + 50331648);
  float* c_s = (float*)(ws + 53477376);
  float* gbuf = (float*)(ws + 59768832);
  float* bias = (float*)(ws + 84934656);
  float* macc = (float*)(ws + 84983808);
  unsigned* bar = (unsigned*)(ws + 88129536);  // [256] bar + [256] tick

  hipMemsetAsync(macc, 0, 3145728, stream);
  hipMemsetAsync(bar, 0, 2048, stream);
  conv_w<<<12288, 256, 0, stream>>>((const f32x4*)Wih, (const f32x4*)Whh,
                                    (u16x4*)Wih_b, (u16x4*)Whh_b);
  init_state<<<1536, 256, 0, stream>>>((const f32x4*)hidden, (const f32x4*)cell,
                                       (const f32x4*)bih, (const f32x4*)bhh,
                                       (u16x4*)h_b, (f32x4*)c_s, (f32x4*)bias);

  // one persistent launch: XCD-local dataflow, 2 blocks/CU, per-XCD barriers
  persist_kernel<<<512, 256, 0, stream>>>(Wih_b, Whh_b, h_b, c_s, gbuf, bias,
                                          macc, W1, W2, bar);

  finalize_k<<<1536, 256, 0, stream>>>(macc, b1, b2, out);
}

// Round 7
// 9181.296 us; speedup vs baseline: 1.4604x; 1.4604x over previous
//
#include <hip/hip_runtime.h>
#include <stdint.h>

// DeepAR decoder: L=3, B=512, H=1024, TAU=96, T=8, BETA=2
// ws layout (bytes):
//   Wih_b  bf16 [3][4096][1024]   @ 0          (25165824)
//   Whh_b  bf16 [3][4096][1024]   @ 25165824   (25165824)
//   h_b    bf16 [3][512][1024]    @ 50331648   (3145728)
//   c_s    f32  [3][512][1024]    @ 53477376   (6291456)
//   gbuf   f32  [3][8M]           @ 59768832   (25165824)  (MFMA C-layout tiles)
//   bias   f32  [3][4096]         @ 84934656   (49152)
//   macc   f32  [512][96][16]     @ 84983808   (3145728)
//   bar    u32[8] stride 32       @ 88129536   (1024)      per-XCD phase counters
//   tick   u32[8] stride 32       @ 88130560   (1024)      per-XCD ticket counters

typedef __attribute__((ext_vector_type(8))) short short8;
typedef __attribute__((ext_vector_type(8))) __bf16 bf16x8_t;
typedef __attribute__((ext_vector_type(4))) float f32x4;
typedef __attribute__((ext_vector_type(4))) unsigned short u16x4;

static __device__ __forceinline__ unsigned short f2bf(float f) {
  unsigned int u = __float_as_uint(f);
  u += 0x7FFFu + ((u >> 16) & 1u);  // RNE
  return (unsigned short)(u >> 16);
}

static __device__ __forceinline__ float sigm(float x) {
  return 1.0f / (1.0f + __expf(-x));
}
static __device__ __forceinline__ float tanh_f(float x) {
  float xc = fminf(fmaxf(x, -15.f), 15.f);
  float e = __expf(2.0f * xc);
  return 1.0f - 2.0f / (e + 1.0f);
}

// aux=1 (sc0/GLC): bypass L1, read the XCD's L2 directly. All cross-BLOCK
// data in this design is same-XCD, so L2 is the coherence point — standard
// within-device GCN semantics, no MALL/cache-maintenance tricks.
static __device__ __forceinline__ void gload_lds16_sc0(const void* g, void* l) {
  __builtin_amdgcn_global_load_lds(
      (const __attribute__((address_space(1))) unsigned int*)g,
      (__attribute__((address_space(3))) unsigned int*)l, 16, 0, 1);
}

static __device__ __forceinline__ f32x4 ld4_sc0(const float* p) {
  f32x4 r;
  asm volatile("global_load_dwordx4 %0, %1, off sc0"
               : "=v"(r) : "v"(p) : "memory");
  return r;
}
#define VMCNT0 asm volatile("s_waitcnt vmcnt(0)" ::: "memory")

static __device__ __forceinline__ f32x4 mfma16(short8 a, short8 b, f32x4 c) {
  return __builtin_amdgcn_mfma_f32_16x16x32_bf16((bf16x8_t)a, (bf16x8_t)b, c, 0, 0, 0);
}

// ---------------------------------------------------------------------------
// PERSISTENT kernel, XCD-LOCAL dataflow (round-5 verified design, 9304 us).
// Round-6 lesson: 2 blocks/CU (launch_bounds(256,2)) crushed VGPR 200->128,
// gutting the register prefetch pipeline -> SLOWER (13.4 ms). This kernel's
// latency hiding lives in REGISTERS, not wave count.
//
// Round-7 single change vs round-5: B-prefetch depth 4 -> 8 (bfr[8][4],
// +128 VGPR, budget ~512/wave at 1 wave/SIMD). Round-5 counters: MFMA busy
// only 3.4 us of 32.2 us/phase; B-loads stream 16 MB/XCD/phase through a
// 4 MB L2 -> MALL latency ~600-900 cy; depth-4 covered only ~300-600 cy of
// MFMA issue. Depth-8 doubles the cover.
//
// grid 256, 256 thr, 96 KB LDS/block -> pigeonhole forces exactly 1 block/CU,
// each XCD hosts exactly 32 blocks. mt = XCC_ID (HW-truthful), (role,hcg) =
// per-XCD ticket. All cross-block dataflow (h_b rows, gbuf tiles, c_s) is
// XCD-local => sc0 loads vs L2 suffice; per-XCD 32-way monotonic barrier,
// no fences, no L2 writeback sweeps.
// ---------------------------------------------------------------------------
__global__ __launch_bounds__(256, 1) void persist_kernel(
    const unsigned short* __restrict__ WihA,  // [3][4096][1024] bf16
    const unsigned short* __restrict__ WhhA,  // [3][4096][1024] bf16
    unsigned short* __restrict__ hB,          // [3][512][1024] bf16
    float* __restrict__ cS,                   // [3][512][1024]
    float* __restrict__ gB,                   // [3][2097152]
    const float* __restrict__ biasA,          // [3][4096]
    float* __restrict__ macc,                 // [512][96][16]
    const float* __restrict__ W1, const float* __restrict__ W2,
    unsigned* __restrict__ bar) {             // [8*32] bar | [8*32] tick
  // plane 0/1: A-chunk double buffer. plane 2: ticket broadcast + LDS pad
  // that forces 1 block/CU (96 KB total).
  __shared__ __align__(16) char ldsA[3][32768];

  unsigned xcc;
  asm volatile("s_getreg_b32 %0, hwreg(HW_REG_XCC_ID)" : "=s"(xcc));
  xcc &= 7u;

  int* shmeta = (int*)ldsA[2];
  if (threadIdx.x == 0) {
    unsigned t = __hip_atomic_fetch_add(bar + 256 + xcc * 32, 1u,
                                        __ATOMIC_RELAXED,
                                        __HIP_MEMORY_SCOPE_AGENT);
    shmeta[0] = (int)t;
  }
  __syncthreads();
  const int ticket = shmeta[0];      // 0..31 within this XCD
  const int mt = (int)xcc;           // m-tile 0..7  (64 batch rows)
  const int role = ticket & 1;       // 0 = x-GEMM+epilogue, 1 = h-partial
  const int hcg = ticket >> 1;       // 0..15 (64 h-cols)
  const int tile = hcg * 8 + mt;     // canonical gbuf tile id (unchanged)
  const int m0 = mt * 64;
  const int hc0 = hcg * 64;
  unsigned* mybar = bar + xcc * 32;

  const int tid = threadIdx.x;
  const int w = tid >> 6;   // wave id: h-col group
  const int lane = tid & 63;
  const int quad = lane >> 4;
  const int l16 = lane & 15;
  const int rbase = tid >> 5;  // 0..7
  const int spos = tid & 31;
  const int wvbase = w * 1024;  // wave-uniform LDS offset within issue
  const int rx0 = l16, rx1 = 16 + l16;

#define STAGE(kc_, buf_)                                                      \
  {                                                                           \
    _Pragma("unroll") for (int j = 0; j < 8; ++j) {                           \
      int r_ = j * 8 + rbase;                                                 \
      int c_ = spos ^ (r_ & 31);                                              \
      gload_lds16_sc0(Ap + (size_t)(m0 + r_) * 1024 + (kc_)*256 + c_ * 8,     \
                      &ldsA[buf_][j * 4096 + wvbase]);                        \
    }                                                                         \
  }

#pragma unroll 1
  for (int p = 0; p < 289; ++p) {
    // p=0: bootstrap (h-partial only, l=2 semantics); p>=1: st=(p-1)/3, l=(p-1)%3
    const int l = (p == 0) ? 2 : (p - 1) % 3;
    const int st = (p == 0) ? 0 : (p - 1) / 3;
    const int lh = (l + 1) % 3;
    const int do_x = (p != 0);
    const int do_h = (p != 288);
    const int do_proj = (p != 0) && (l == 2);
    const int active = role ? do_h : do_x;

    if (active) {
      const unsigned short* Wp;
      const unsigned short* Ap;
      if (role) {
        Wp = WhhA + (size_t)lh * 4194304;
        Ap = hB + (size_t)lh * 524288;
      } else {
        Wp = WihA + (size_t)l * 4194304;
        Ap = hB + (size_t)((l == 0) ? 2 : (l - 1)) * 524288;
      }

      // B rows (weights, direct-to-register): gate g, col hc0 + w*16 + l16
      const unsigned short* brow[4];
#pragma unroll
      for (int g = 0; g < 4; ++g)
        brow[g] = Wp + (size_t)(g * 1024 + hc0 + w * 16 + l16) * 1024 + quad * 8;

      // prologue: stage chunk 0, B prefetch depth 8, acc init
      STAGE(0, 0);
      short8 bfr[8][4];
#pragma unroll
      for (int d = 0; d < 8; ++d)
#pragma unroll
        for (int g = 0; g < 4; ++g) bfr[d][g] = *(const short8*)(brow[g] + d * 32);

      f32x4 acc[4][4];
      if (role == 0) {
        const float* gb_rd = gB + (size_t)l * 2097152;
#pragma unroll
        for (int mb = 0; mb < 4; ++mb)
#pragma unroll
          for (int g = 0; g < 4; ++g)
            acc[mb][g] = ld4_sc0(
                gb_rd + ((size_t)(tile * 4 + w) * 16 + g * 4 + mb) * 256 + lane * 4);
        VMCNT0;                              // asm loads valid before use
        __builtin_amdgcn_sched_barrier(0);   // rule #18: pin use after wait
      } else {
        f32x4 z4 = {0.f, 0.f, 0.f, 0.f};
#pragma unroll
        for (int mb = 0; mb < 4; ++mb)
#pragma unroll
          for (int g = 0; g < 4; ++g) acc[mb][g] = z4;
      }
      __syncthreads();  // chunk 0 staged

#pragma unroll
      for (int kc = 0; kc < 4; ++kc) {
        if (kc < 3) STAGE(kc + 1, (kc + 1) & 1);
        const char* base = ldsA[kc & 1];
        short8 afr[2][4];
#pragma unroll
        for (int mb = 0; mb < 4; ++mb) {
          int rxm = (mb & 1) ? rx1 : rx0;
          afr[0][mb] =
              *(const short8*)(base + (mb * 16 + l16) * 512 + ((quad ^ rxm) << 4));
        }
#pragma unroll
        for (int ks = 0; ks < 8; ++ks) {
          const int kg = kc * 8 + ks;
          short8 a0 = afr[ks & 1][0], a1 = afr[ks & 1][1];
          short8 a2 = afr[ks & 1][2], a3 = afr[ks & 1][3];
          short8 b0 = bfr[kg & 7][0], b1 = bfr[kg & 7][1];
          short8 b2 = bfr[kg & 7][2], b3 = bfr[kg & 7][3];
          if (ks < 7) {
#pragma unroll
            for (int mb = 0; mb < 4; ++mb) {
              int rxm = (mb & 1) ? rx1 : rx0;
              afr[(ks + 1) & 1][mb] =
                  *(const short8*)(base + (mb * 16 + l16) * 512 +
                                   ((((ks + 1) * 4 + quad) ^ rxm) << 4));
            }
          }
          if (kg + 8 < 32) {  // depth-8 B prefetch (~1200-2500 cyc cover)
#pragma unroll
            for (int g = 0; g < 4; ++g)
              bfr[kg & 7][g] = *(const short8*)(brow[g] + (kg + 8) * 32);
          }
          acc[0][0] = mfma16(a0, b0, acc[0][0]);
          acc[1][0] = mfma16(a1, b0, acc[1][0]);
          acc[2][0] = mfma16(a2, b0, acc[2][0]);
          acc[3][0] = mfma16(a3, b0, acc[3][0]);
          acc[0][1] = mfma16(a0, b1, acc[0][1]);
          acc[1][1] = mfma16(a1, b1, acc[1][1]);
          acc[2][1] = mfma16(a2, b1, acc[2][1]);
          acc[3][1] = mfma16(a3, b1, acc[3][1]);
          acc[0][2] = mfma16(a0, b2, acc[0][2]);
          acc[1][2] = mfma16(a1, b2, acc[1][2]);
          acc[2][2] = mfma16(a2, b2, acc[2][2]);
          acc[3][2] = mfma16(a3, b2, acc[3][2]);
          acc[0][3] = mfma16(a0, b3, acc[0][3]);
          acc[1][3] = mfma16(a1, b3, acc[1][3]);
          acc[2][3] = mfma16(a2, b3, acc[2][3]);
          acc[3][3] = mfma16(a3, b3, acc[3][3]);
        }
        if (kc < 3) __syncthreads();
      }

      if (role == 1) {
        // recurrent partial -> gbuf (plain stores land in this XCD's L2;
        // consumer x-role is same-XCD and reads with sc0)
        float* gb_wr = gB + (size_t)lh * 2097152;
#pragma unroll
        for (int mb = 0; mb < 4; ++mb)
#pragma unroll
          for (int g = 0; g < 4; ++g)
            *(f32x4*)(gb_wr + ((size_t)(tile * 4 + w) * 16 + g * 4 + mb) * 256 +
                      lane * 4) = acc[mb][g];
      } else {
        // ---- x-role epilogue: all 4 gates in-lane -> c,h (register only) ----
        float* c_l = cS + (size_t)l * 524288;
        unsigned short* h_out = hB + (size_t)l * 524288;
        const float* bias_l = biasA + l * 4096;
        const int colh = hc0 + w * 16 + l16;
        float bs0 = bias_l[colh];
        float bs1 = bias_l[1024 + colh];
        float bs2 = bias_l[2048 + colh];
        float bs3 = bias_l[3072 + colh];
        float hv[16];
#pragma unroll
        for (int mb = 0; mb < 4; ++mb) {
#pragma unroll
          for (int rr = 0; rr < 4; ++rr) {
            int row = m0 + mb * 16 + quad * 4 + rr;
            float gi = acc[mb][0][rr] + bs0;
            float gf = acc[mb][1][rr] + bs1;
            float gg = acc[mb][2][rr] + bs2;
            float go = acc[mb][3][rr] + bs3;
            float* cp = c_l + (size_t)row * 1024 + colh;
            float cn = sigm(gf) * (*cp) + sigm(gi) * tanh_f(gg);
            *cp = cn;
            float h = sigm(go) * tanh_f(cn);
            hv[mb * 4 + rr] = h;
            h_out[(size_t)row * 1024 + colh] = f2bf(h);
          }
        }

        if (do_proj) {
          // fused projection over this WG's 64 h-cols; reuse dead A LDS bufs.
          float* hbuf = (float*)ldsA[0];
          float* projred = (float*)ldsA[1];
#pragma unroll
          for (int mb = 0; mb < 4; ++mb)
#pragma unroll
            for (int rr = 0; rr < 4; ++rr)
              hbuf[(mb * 16 + quad * 4 + rr) * 65 + w * 16 + l16] = hv[mb * 4 + rr];
          __syncthreads();

          const int m = tid & 63;
          const int grp = tid >> 6;  // 16-col group
          float pm[8], ps[8];
          float hj[16];
#pragma unroll
          for (int j = 0; j < 16; ++j) hj[j] = hbuf[m * 65 + grp * 16 + j];
#pragma unroll
          for (int tt = 0; tt < 8; ++tt) {
            const f32x4* w1p = (const f32x4*)(W1 + tt * 1024 + hc0 + grp * 16);
            const f32x4* w2p = (const f32x4*)(W2 + tt * 1024 + hc0 + grp * 16);
            float s1 = 0.f, s2 = 0.f;
#pragma unroll
            for (int v = 0; v < 4; ++v) {
              f32x4 wa = w1p[v], wb = w2p[v];
#pragma unroll
              for (int j = 0; j < 4; ++j) {
                s1 += hj[v * 4 + j] * wa[j];
                s2 += hj[v * 4 + j] * wb[j];
              }
            }
            pm[tt] = s1;
            ps[tt] = s2;
          }
#pragma unroll
          for (int tt = 0; tt < 8; ++tt) {
            projred[(grp * 64 + m) * 17 + tt] = pm[tt];
            projred[(grp * 64 + m) * 17 + 8 + tt] = ps[tt];
          }
          __syncthreads();
#pragma unroll
          for (int q = 0; q < 4; ++q) {
            int s = grp * 4 + q;
            float v = projred[m * 17 + s] + projred[(64 + m) * 17 + s] +
                      projred[(128 + m) * 17 + s] + projred[(192 + m) * 17 + s];
            atomicAdd(&macc[((size_t)(m0 + m) * 96 + st) * 16 + s], v);
          }
        }
      }
    }

    // ---- per-XCD barrier (32 blocks), fence-free ----
    if (p < 288) {
      VMCNT0;           // belt-and-braces: this wave's stores drained
      __syncthreads();  // all waves' stores in L2 before arrival
      if (tid == 0) {
        __hip_atomic_fetch_add(mybar, 1u, __ATOMIC_RELAXED,
                               __HIP_MEMORY_SCOPE_AGENT);
        const unsigned tgt = 32u * (unsigned)(p + 1);  // monotonic counter
        while (__hip_atomic_load(mybar, __ATOMIC_RELAXED,
                                 __HIP_MEMORY_SCOPE_AGENT) < tgt)
          __builtin_amdgcn_s_sleep(2);
      }
      asm volatile("" ::: "memory");  // no load hoisting above the spin
      __syncthreads();
    }
  }
#undef STAGE
}

// ---------------------------------------------------------------------------
__global__ void conv_w(const f32x4* __restrict__ wi, const f32x4* __restrict__ wh,
                       u16x4* __restrict__ wib, u16x4* __restrict__ whb) {
  int i = blockIdx.x * 256 + threadIdx.x;  // 3145728 vec4
  f32x4 a = wi[i], b = wh[i];
  u16x4 pa, pb;
#pragma unroll
  for (int j = 0; j < 4; ++j) {
    pa[j] = f2bf(a[j]);
    pb[j] = f2bf(b[j]);
  }
  wib[i] = pa;
  whb[i] = pb;
}

__global__ void init_state(const f32x4* __restrict__ hid, const f32x4* __restrict__ cel,
                           const f32x4* __restrict__ bih, const f32x4* __restrict__ bhh,
                           u16x4* __restrict__ hb, f32x4* __restrict__ cs,
                           f32x4* __restrict__ bias) {
  int i = blockIdx.x * 256 + threadIdx.x;  // 393216 vec4
  f32x4 h = hid[i];
  u16x4 p;
#pragma unroll
  for (int j = 0; j < 4; ++j) p[j] = f2bf(h[j]);
  hb[i] = p;
  cs[i] = cel[i];
  if (i < 3072) bias[i] = bih[i] + bhh[i];
}

__global__ void finalize_k(const float* __restrict__ macc, const float* __restrict__ b1,
                           const float* __restrict__ b2, float* __restrict__ out) {
  int idx = blockIdx.x * 256 + threadIdx.x;  // 393216 = 512*96*8
  int t = idx & 7;
  int bt = idx >> 3;  // b*96+tau
  float mu = macc[bt * 16 + t] + b1[t];
  float z2 = 2.0f * (macc[bt * 16 + 8 + t] + b2[t]);
  float sp = fmaxf(z2, 0.f) + log1pf(__expf(-fabsf(z2)));
  out[idx] = mu;
  out[393216 + idx] = 0.5f * sp;
}

// ---------------------------------------------------------------------------
extern "C" void kernel_launch(void* const* d_in, const int* in_sizes, int n_in,
                              void* d_out, int out_size, void* d_ws, size_t ws_size,
                              hipStream_t stream) {
  (void)in_sizes; (void)n_in; (void)out_size; (void)ws_size;
  const float* hidden = (const float*)d_in[0];
  const float* cell = (const float*)d_in[1];
  const float* Wih = (const float*)d_in[2];
  const float* Whh = (const float*)d_in[3];
  const float* bih = (const float*)d_in[4];
  const float* bhh = (const float*)d_in[5];
  const float* W1 = (const float*)d_in[6];
  const float* b1 = (const float*)d_in[7];
  const float* W2 = (const float*)d_in[8];
  const float* b2 = (const float*)d_in[9];
  float* out = (float*)d_out;

  char* ws = (char*)d_ws;
  unsigned short* Wih_b = (unsigned short*)(ws);
  unsigned short* Whh_b = (unsigned short*)(ws + 25165824);
  unsigned short* h_b = (unsigned short*)(ws + 50331648);
  float* c_s = (float*)(ws + 53477376);
  float* gbuf = (float*)(ws + 59768832);
  float* bias = (float*)(ws + 84934656);
  float* macc = (float*)(ws + 84983808);
  unsigned* bar = (unsigned*)(ws + 88129536);  // [256] bar + [256] tick

  hipMemsetAsync(macc, 0, 3145728, stream);
  hipMemsetAsync(bar, 0, 2048, stream);
  conv_w<<<12288, 256, 0, stream>>>((const f32x4*)Wih, (const f32x4*)Whh,
                                    (u16x4*)Wih_b, (u16x4*)Whh_b);
  init_state<<<1536, 256, 0, stream>>>((const f32x4*)hidden, (const f32x4*)cell,
                                       (const f32x4*)bih, (const f32x4*)bhh,
                                       (u16x4*)h_b, (f32x4*)c_s, (f32x4*)bias);

  // one persistent launch: XCD-local dataflow, per-XCD barriers
  persist_kernel<<<256, 256, 0, stream>>>(Wih_b, Whh_b, h_b, c_s, gbuf, bias,
                                          macc, W1, W2, bar);

  finalize_k<<<1536, 256, 0, stream>>>(macc, b1, b2, out);
}